// Round 10
// baseline (536.366 us; speedup 1.0000x reference)
//
#include <hip/hip_runtime.h>
#include <cstdint>

#define NN 100000
#define EE 3200000
#define SB_BITS 8
#define SB_NODES (1 << SB_BITS)                    // 256 nodes / superbucket
#define NSB ((NN + SB_NODES - 1) / SB_NODES)       // 391 superbuckets
#define CAP 9216                                   // max edges/sb in LDS (mean 8192, +11 sigma)
#define CH 4096                                    // edges per multisplit chunk
#define EPT (CH / 256)                             // 16 edges per thread

__device__ inline float4 add4(float4 a, float4 b) {
    return make_float4(a.x + b.x, a.y + b.y, a.z + b.z, a.w + b.w);
}

// pack two fp32 -> bf16x2 (RNE), lo in low half
__device__ inline unsigned pk_bf2(float lo, float hi) {
    unsigned a = __float_as_uint(lo);
    unsigned b = __float_as_uint(hi);
    a = (a + 0x7FFFu + ((a >> 16) & 1u)) >> 16;
    b = (b + 0x7FFFu + ((b >> 16) & 1u)) & 0xFFFF0000u;
    return a | b;
}

// ---------------- CSR build ----------------

// superbucket histogram (LDS-staged, flushed once per block)
__global__ void k_hist_sb(const int* __restrict__ dst, int* __restrict__ scnt) {
    __shared__ int h[NSB];
    for (int i = threadIdx.x; i < NSB; i += 256) h[i] = 0;
    __syncthreads();
    for (int e = blockIdx.x * 256 + threadIdx.x; e < EE; e += gridDim.x * 256)
        atomicAdd(&h[dst[e] >> SB_BITS], 1);
    __syncthreads();
    for (int i = threadIdx.x; i < NSB; i += 256) {
        int v = h[i];
        if (v) atomicAdd(&scnt[i], v);
    }
}

// single-block exclusive scan of NSB (<=512) superbucket counts
__global__ void k_scan_sb(const int* __restrict__ scnt,
                          int* __restrict__ sbptr, int* __restrict__ cursor) {
    __shared__ int sm[512];
    int i = threadIdx.x;   // 256 threads, each owns slots i and i+256
    int v0 = (i < NSB) ? scnt[i] : 0;
    int v1 = (i + 256 < NSB) ? scnt[i + 256] : 0;
    sm[i] = v0;
    sm[i + 256] = v1;
    __syncthreads();
    for (int o = 1; o < 512; o <<= 1) {
        int a0 = (i >= o) ? sm[i - o] : 0;
        int a1 = (i + 256 >= o) ? sm[i + 256 - o] : 0;
        __syncthreads();
        sm[i] += a0;
        sm[i + 256] += a1;
        __syncthreads();
    }
    if (i < NSB)       { sbptr[i]       = sm[i] - v0;       cursor[i]       = sm[i] - v0; }
    if (i + 256 < NSB) { sbptr[i + 256] = sm[i + 256] - v1; cursor[i + 256] = sm[i + 256] - v1; }
    if (i == 0) sbptr[NSB] = sm[511];   // == EE
}

// LDS multisplit: chunk of 4096 edges -> 391 bins, reorder in LDS,
// one global-cursor atomic per (bin,chunk), contiguous burst writes.
__global__ void k_split(const int* __restrict__ src, const int* __restrict__ dst,
                        int* __restrict__ cursor, int* __restrict__ out) {
    __shared__ int hist[512];     // padded to 512 for the scan
    __shared__ int lbase[NSB];
    __shared__ int gbase[NSB];
    __shared__ int buf[CH];
    __shared__ unsigned short keyb[CH];
    const int nchunks = (EE + CH - 1) / CH;
    for (int c = blockIdx.x; c < nchunks; c += gridDim.x) {
        int base = c * CH;
        int cnt = min(CH, EE - base);
        hist[threadIdx.x] = 0;
        hist[threadIdx.x + 256] = 0;
        __syncthreads();
        int words[EPT], ranks[EPT], keys[EPT];
        #pragma unroll
        for (int k = 0; k < EPT; ++k) {
            int idx = threadIdx.x + k * 256;
            if (idx < cnt) {
                int d = dst[base + idx];
                int s = src[base + idx];
                int key = d >> SB_BITS;
                words[k] = s | ((d & (SB_NODES - 1)) << 17);
                keys[k] = key;
                ranks[k] = atomicAdd(&hist[key], 1);
            } else keys[k] = -1;
        }
        __syncthreads();
        // 512-slot Hillis-Steele inclusive scan (thread owns i and i+256)
        int i = threadIdx.x;
        int v0 = hist[i], v1 = hist[i + 256];
        for (int o = 1; o < 512; o <<= 1) {
            int a0 = (i >= o) ? hist[i - o] : 0;
            int a1 = (i + 256 >= o) ? hist[i + 256 - o] : 0;
            __syncthreads();
            hist[i] += a0;
            hist[i + 256] += a1;
            __syncthreads();
        }
        if (i < NSB) {
            lbase[i] = hist[i] - v0;
            gbase[i] = (v0 > 0) ? atomicAdd(&cursor[i], v0) : 0;
        }
        if (i + 256 < NSB) {
            lbase[i + 256] = hist[i + 256] - v1;
            gbase[i + 256] = (v1 > 0) ? atomicAdd(&cursor[i + 256], v1) : 0;
        }
        __syncthreads();
        #pragma unroll
        for (int k = 0; k < EPT; ++k) {
            if (keys[k] >= 0) {
                int p = lbase[keys[k]] + ranks[k];
                buf[p] = words[k];
                keyb[p] = (unsigned short)keys[k];
            }
        }
        __syncthreads();
        for (int j = threadIdx.x; j < cnt; j += 256) {
            int kk = keyb[j];
            out[gbase[kk] + (j - lbase[kk])] = buf[j];
        }
        __syncthreads();
    }
}

// one block per superbucket: per-node counting sort via LDS staging,
// sorted result copied to global with fully sequential coalesced stores.
__global__ void k_sb_sort(const int* __restrict__ sbptr, const int* __restrict__ packed,
                          int* __restrict__ csr_src, int* __restrict__ rowptr) {
    __shared__ int hist[SB_NODES];   // -> exclusive offsets -> cursors
    __shared__ int lbuf[CAP];
    int b = blockIdx.x;
    int e0 = sbptr[b], e1 = sbptr[b + 1];
    int cnt = e1 - e0;
    hist[threadIdx.x] = 0;
    __syncthreads();
    for (int j = e0 + threadIdx.x; j < e1; j += 256)
        atomicAdd(&hist[(packed[j] >> 17) & (SB_NODES - 1)], 1);
    __syncthreads();
    // 256-slot inclusive scan, one slot per thread
    int i = threadIdx.x;
    int v = hist[i];
    for (int o = 1; o < 256; o <<= 1) {
        int a = (i >= o) ? hist[i - o] : 0;
        __syncthreads();
        hist[i] += a;
        __syncthreads();
    }
    int excl = hist[i] - v;
    int node = (b << SB_BITS) + i;
    if (node < NN) rowptr[node] = e0 + excl;
    hist[i] = excl;                   // becomes cursor
    if (b == 0 && i == 0) rowptr[NN] = EE;
    __syncthreads();
    if (cnt <= CAP) {
        for (int j = e0 + threadIdx.x; j < e1; j += 256) {
            int w = packed[j];
            int n = (w >> 17) & (SB_NODES - 1);
            int pos = atomicAdd(&hist[n], 1);
            lbuf[pos] = w & 0x1FFFF;
        }
        __syncthreads();
        for (int j = threadIdx.x; j < cnt; j += 256)
            csr_src[e0 + j] = lbuf[j];           // sequential coalesced
    } else {
        // overflow fallback (unreachable for this input): direct global scatter
        for (int j = e0 + threadIdx.x; j < e1; j += 256) {
            int w = packed[j];
            int n = (w >> 17) & (SB_NODES - 1);
            int pos = atomicAdd(&hist[n], 1);
            csr_src[e0 + pos] = w & 0x1FFFF;
        }
    }
}

// ---------------- GNN compute ----------------

// Fused: t_bf[node] = bf16(h[node]@Wn), hout[node] = h[node]@Ws + bn.
// One thread per node, 64 fp32 accumulators. Wn/Ws are uniform pointers
// -> s_load; h tile cooperatively staged in LDS with full-line coalesced
// float4 reads (16 rows x 64B per wave instruction).
template <int DIN>
__global__ __launch_bounds__(256) void k_transform(
        const float* __restrict__ h,
        const float* __restrict__ Wn,
        const float* __restrict__ Ws,
        const float* __restrict__ bn,
        unsigned* __restrict__ t_bf,
        float* __restrict__ hout) {
    constexpr int KC = 16;
    constexpr int V4 = KC / 4;                      // float4 per row-chunk
    __shared__ float hs[256 * (KC + 1)];
    const int node0 = blockIdx.x * 256;
    const int node = node0 + threadIdx.x;
    const bool valid = node < NN;
    float an[32], as[32];
    #pragma unroll
    for (int d = 0; d < 32; ++d) { an[d] = 0.f; as[d] = 0.f; }
    for (int kc = 0; kc < DIN; kc += KC) {
        __syncthreads();
        #pragma unroll
        for (int it = 0; it < V4; ++it) {
            int idx = threadIdx.x + it * 256;       // 0..1023
            int row = idx >> 2;                     // 0..255
            int col = (idx & 3) * 4;
            int rnode = node0 + row;
            const float* p = h + (size_t)(rnode < NN ? rnode : NN - 1) * DIN + kc + col;
            float4 f = *(const float4*)p;
            hs[row * (KC + 1) + col + 0] = f.x;
            hs[row * (KC + 1) + col + 1] = f.y;
            hs[row * (KC + 1) + col + 2] = f.z;
            hs[row * (KC + 1) + col + 3] = f.w;
        }
        __syncthreads();
        #pragma unroll
        for (int kk = 0; kk < KC; ++kk) {
            float f = hs[threadIdx.x * (KC + 1) + kk];
            const float* __restrict__ w0 = Wn + (kc + kk) * 32;   // uniform -> s_load
            const float* __restrict__ w1 = Ws + (kc + kk) * 32;
            #pragma unroll
            for (int d = 0; d < 32; ++d) an[d] = fmaf(f, w0[d], an[d]);
            #pragma unroll
            for (int d = 0; d < 32; ++d) as[d] = fmaf(f, w1[d], as[d]);
        }
    }
    if (valid) {
        // t in bf16 (RNE), 16 uints = 64 B per node
        unsigned tb[16];
        #pragma unroll
        for (int d = 0; d < 16; ++d) tb[d] = pk_bf2(an[2 * d], an[2 * d + 1]);
        unsigned* tp = t_bf + (size_t)node * 16;
        #pragma unroll
        for (int d = 0; d < 16; d += 4)
            *(uint4*)(tp + d) = make_uint4(tb[d], tb[d + 1], tb[d + 2], tb[d + 3]);
        float* __restrict__ hp = hout + (size_t)node * 32;
        #pragma unroll
        for (int d = 0; d < 32; d += 4)
            *(float4*)(hp + d) = make_float4(as[d] + bn[d], as[d + 1] + bn[d + 1],
                                             as[d + 2] + bn[d + 2], as[d + 3] + bn[d + 3]);
    }
}

// 8 lanes per node, one bf16x4 (uint2, 8B) per lane = 64B/row = 1 line/edge.
// fp32 accumulate, 4-deep unroll: hout = relu(hout + seg_sum(t))
__global__ void k_aggregate(const int* __restrict__ rowptr,
                            const int* __restrict__ csr_src,
                            const uint2* __restrict__ t2,
                            float4* __restrict__ hout4) {
    int node = blockIdx.x * 32 + (threadIdx.x >> 3);
    int q = threadIdx.x & 7;
    if (node >= NN) return;
    int j = rowptr[node];
    int end = rowptr[node + 1];
    float4 a0 = make_float4(0.f, 0.f, 0.f, 0.f);
    float4 a1 = a0, a2 = a0, a3 = a0;
    for (; j + 4 <= end; j += 4) {
        int s0 = csr_src[j];
        int s1 = csr_src[j + 1];
        int s2 = csr_src[j + 2];
        int s3 = csr_src[j + 3];
        uint2 u0 = t2[s0 * 8 + q];
        uint2 u1 = t2[s1 * 8 + q];
        uint2 u2 = t2[s2 * 8 + q];
        uint2 u3 = t2[s3 * 8 + q];
        a0.x += __uint_as_float(u0.x << 16); a0.y += __uint_as_float(u0.x & 0xFFFF0000u);
        a0.z += __uint_as_float(u0.y << 16); a0.w += __uint_as_float(u0.y & 0xFFFF0000u);
        a1.x += __uint_as_float(u1.x << 16); a1.y += __uint_as_float(u1.x & 0xFFFF0000u);
        a1.z += __uint_as_float(u1.y << 16); a1.w += __uint_as_float(u1.y & 0xFFFF0000u);
        a2.x += __uint_as_float(u2.x << 16); a2.y += __uint_as_float(u2.x & 0xFFFF0000u);
        a2.z += __uint_as_float(u2.y << 16); a2.w += __uint_as_float(u2.y & 0xFFFF0000u);
        a3.x += __uint_as_float(u3.x << 16); a3.y += __uint_as_float(u3.x & 0xFFFF0000u);
        a3.z += __uint_as_float(u3.y << 16); a3.w += __uint_as_float(u3.y & 0xFFFF0000u);
    }
    for (; j < end; ++j) {
        uint2 u = t2[csr_src[j] * 8 + q];
        a0.x += __uint_as_float(u.x << 16); a0.y += __uint_as_float(u.x & 0xFFFF0000u);
        a0.z += __uint_as_float(u.y << 16); a0.w += __uint_as_float(u.y & 0xFFFF0000u);
    }
    float4 s = add4(add4(a0, a1), add4(a2, a3));
    int idx = node * 8 + q;
    float4 h = hout4[idx];
    h.x = fmaxf(h.x + s.x, 0.f);
    h.y = fmaxf(h.y + s.y, 0.f);
    h.z = fmaxf(h.z + s.z, 0.f);
    h.w = fmaxf(h.w + s.w, 0.f);
    hout4[idx] = h;
}

// concat(x,h1,h2,h3) @ fc_w + fc_b -> log_softmax
__global__ void k_final(const float* __restrict__ x,
                        const float* __restrict__ h1,
                        const float* __restrict__ h2,
                        const float* __restrict__ h3,
                        const float* __restrict__ fc_w,
                        const float* __restrict__ fc_b,
                        float* __restrict__ out) {
    __shared__ float Wl[224 * 10];
    __shared__ float bl[10];
    for (int i = threadIdx.x; i < 224 * 10; i += blockDim.x) Wl[i] = fc_w[i];
    if (threadIdx.x < 10) bl[threadIdx.x] = fc_b[threadIdx.x];
    __syncthreads();
    int n = blockIdx.x * blockDim.x + threadIdx.x;
    if (n >= NN) return;
    float acc[10];
    #pragma unroll
    for (int c = 0; c < 10; ++c) acc[c] = bl[c];
    const float* xr = x + (size_t)n * 128;
    for (int j = 0; j < 128; ++j) {
        float f = xr[j];
        #pragma unroll
        for (int c = 0; c < 10; ++c) acc[c] += f * Wl[j * 10 + c];
    }
    const float* hs[3] = {h1, h2, h3};
    for (int l = 0; l < 3; ++l) {
        const float* hr = hs[l] + (size_t)n * 32;
        for (int j = 0; j < 32; ++j) {
            float f = hr[j];
            #pragma unroll
            for (int c = 0; c < 10; ++c) acc[c] += f * Wl[(128 + l * 32 + j) * 10 + c];
        }
    }
    float m = acc[0];
    #pragma unroll
    for (int c = 1; c < 10; ++c) m = fmaxf(m, acc[c]);
    float s = 0.f;
    #pragma unroll
    for (int c = 0; c < 10; ++c) s += __expf(acc[c] - m);
    float ls = __logf(s);
    #pragma unroll
    for (int c = 0; c < 10; ++c) out[n * 10 + c] = acc[c] - m - ls;
}

extern "C" void kernel_launch(void* const* d_in, const int* in_sizes, int n_in,
                              void* d_out, int out_size, void* d_ws, size_t ws_size,
                              hipStream_t stream) {
    const float* x   = (const float*)d_in[0];
    const int*   src = (const int*)d_in[1];
    const int*   dst = (const int*)d_in[2];
    const float* Wn[3] = {(const float*)d_in[3], (const float*)d_in[6], (const float*)d_in[9]};
    const float* bn[3] = {(const float*)d_in[4], (const float*)d_in[7], (const float*)d_in[10]};
    const float* Ws[3] = {(const float*)d_in[5], (const float*)d_in[8], (const float*)d_in[11]};
    const float* fc_w = (const float*)d_in[12];
    const float* fc_b = (const float*)d_in[13];
    float* out = (float*)d_out;

    // workspace layout (packed aliases h3: packed is dead before h3 is written)
    char* w = (char*)d_ws;
    const size_t NF = (size_t)NN * 32;
    unsigned* t_bf = (unsigned*)w;              w += (size_t)NN * 16 * 4;  // 6.4 MB (bf16 t)
    float* h1  = (float*)w;                     w += NF * 4;
    float* h2  = (float*)w;                     w += NF * 4;
    float* h3  = (float*)w;                     w += NF * 4;
    int* csr_src = (int*)w;                     w += (size_t)EE * 4;  // 12.8 MB
    int* scnt   = (int*)w;                      w += (size_t)NSB * 4;
    int* sbptr  = (int*)w;                      w += (size_t)(NSB + 1) * 4;
    int* cursor = (int*)w;                      w += (size_t)NSB * 4;
    int* rowptr = (int*)w;                      w += (size_t)(NN + 1) * 4;
    int* packed = (int*)h3;   // temp, consumed by k_sb_sort before layers run

    // ---- CSR build: multisplit into 391 superbuckets + in-LDS counting sort ----
    hipMemsetAsync(scnt, 0, (size_t)NSB * 4, stream);
    k_hist_sb<<<512, 256, 0, stream>>>(dst, scnt);
    k_scan_sb<<<1, 256, 0, stream>>>(scnt, sbptr, cursor);
    k_split<<<512, 256, 0, stream>>>(src, dst, cursor, packed);
    k_sb_sort<<<NSB, 256, 0, stream>>>(sbptr, packed, csr_src, rowptr);

    // ---- layers ----
    const int tr_blocks = (NN + 255) / 256;   // 391
    const int ag_blocks = (NN + 31) / 32;
    k_transform<128><<<tr_blocks, 256, 0, stream>>>(x, Wn[0], Ws[0], bn[0], t_bf, h1);
    k_aggregate<<<ag_blocks, 256, 0, stream>>>(rowptr, csr_src, (const uint2*)t_bf, (float4*)h1);
    k_transform<32><<<tr_blocks, 256, 0, stream>>>(h1, Wn[1], Ws[1], bn[1], t_bf, h2);
    k_aggregate<<<ag_blocks, 256, 0, stream>>>(rowptr, csr_src, (const uint2*)t_bf, (float4*)h2);
    k_transform<32><<<tr_blocks, 256, 0, stream>>>(h2, Wn[2], Ws[2], bn[2], t_bf, h3);
    k_aggregate<<<ag_blocks, 256, 0, stream>>>(rowptr, csr_src, (const uint2*)t_bf, (float4*)h3);
    k_final<<<(NN + 255) / 256, 256, 0, stream>>>(x, h1, h2, h3, fc_w, fc_b, out);
}

// Round 11
// 442.753 us; speedup vs baseline: 1.2114x; 1.2114x over previous
//
#include <hip/hip_runtime.h>
#include <cstdint>

#define NN 100000
#define EE 3200000
#define SB_BITS 8
#define SB_NODES (1 << SB_BITS)                    // 256 nodes / superbucket
#define NSB ((NN + SB_NODES - 1) / SB_NODES)       // 391 superbuckets
#define CAP 9216                                   // max edges/sb in LDS (mean 8192, +11 sigma)
#define CH 4096                                    // edges per multisplit chunk
#define EPT (CH / 256)                             // 16 edges per thread

__device__ inline float4 add4(float4 a, float4 b) {
    return make_float4(a.x + b.x, a.y + b.y, a.z + b.z, a.w + b.w);
}

// pack two fp32 -> bf16x2 (RNE), lo in low half
__device__ inline unsigned pk_bf2(float lo, float hi) {
    unsigned a = __float_as_uint(lo);
    unsigned b = __float_as_uint(hi);
    a = (a + 0x7FFFu + ((a >> 16) & 1u)) >> 16;
    b = (b + 0x7FFFu + ((b >> 16) & 1u)) & 0xFFFF0000u;
    return a | b;
}

// ---------------- CSR build ----------------

// superbucket histogram (LDS-staged, flushed once per block)
__global__ void k_hist_sb(const int* __restrict__ dst, int* __restrict__ scnt) {
    __shared__ int h[NSB];
    for (int i = threadIdx.x; i < NSB; i += 256) h[i] = 0;
    __syncthreads();
    for (int e = blockIdx.x * 256 + threadIdx.x; e < EE; e += gridDim.x * 256)
        atomicAdd(&h[dst[e] >> SB_BITS], 1);
    __syncthreads();
    for (int i = threadIdx.x; i < NSB; i += 256) {
        int v = h[i];
        if (v) atomicAdd(&scnt[i], v);
    }
}

// single-block exclusive scan of NSB (<=512) superbucket counts
__global__ void k_scan_sb(const int* __restrict__ scnt,
                          int* __restrict__ sbptr, int* __restrict__ cursor) {
    __shared__ int sm[512];
    int i = threadIdx.x;   // 256 threads, each owns slots i and i+256
    int v0 = (i < NSB) ? scnt[i] : 0;
    int v1 = (i + 256 < NSB) ? scnt[i + 256] : 0;
    sm[i] = v0;
    sm[i + 256] = v1;
    __syncthreads();
    for (int o = 1; o < 512; o <<= 1) {
        int a0 = (i >= o) ? sm[i - o] : 0;
        int a1 = (i + 256 >= o) ? sm[i + 256 - o] : 0;
        __syncthreads();
        sm[i] += a0;
        sm[i + 256] += a1;
        __syncthreads();
    }
    if (i < NSB)       { sbptr[i]       = sm[i] - v0;       cursor[i]       = sm[i] - v0; }
    if (i + 256 < NSB) { sbptr[i + 256] = sm[i + 256] - v1; cursor[i + 256] = sm[i + 256] - v1; }
    if (i == 0) sbptr[NSB] = sm[511];   // == EE
}

// LDS multisplit: chunk of 4096 edges -> 391 bins, reorder in LDS,
// one global-cursor atomic per (bin,chunk), contiguous burst writes.
__global__ void k_split(const int* __restrict__ src, const int* __restrict__ dst,
                        int* __restrict__ cursor, int* __restrict__ out) {
    __shared__ int hist[512];     // padded to 512 for the scan
    __shared__ int lbase[NSB];
    __shared__ int gbase[NSB];
    __shared__ int buf[CH];
    __shared__ unsigned short keyb[CH];
    const int nchunks = (EE + CH - 1) / CH;
    for (int c = blockIdx.x; c < nchunks; c += gridDim.x) {
        int base = c * CH;
        int cnt = min(CH, EE - base);
        hist[threadIdx.x] = 0;
        hist[threadIdx.x + 256] = 0;
        __syncthreads();
        int words[EPT], ranks[EPT], keys[EPT];
        #pragma unroll
        for (int k = 0; k < EPT; ++k) {
            int idx = threadIdx.x + k * 256;
            if (idx < cnt) {
                int d = dst[base + idx];
                int s = src[base + idx];
                int key = d >> SB_BITS;
                words[k] = s | ((d & (SB_NODES - 1)) << 17);
                keys[k] = key;
                ranks[k] = atomicAdd(&hist[key], 1);
            } else keys[k] = -1;
        }
        __syncthreads();
        // 512-slot Hillis-Steele inclusive scan (thread owns i and i+256)
        int i = threadIdx.x;
        int v0 = hist[i], v1 = hist[i + 256];
        for (int o = 1; o < 512; o <<= 1) {
            int a0 = (i >= o) ? hist[i - o] : 0;
            int a1 = (i + 256 >= o) ? hist[i + 256 - o] : 0;
            __syncthreads();
            hist[i] += a0;
            hist[i + 256] += a1;
            __syncthreads();
        }
        if (i < NSB) {
            lbase[i] = hist[i] - v0;
            gbase[i] = (v0 > 0) ? atomicAdd(&cursor[i], v0) : 0;
        }
        if (i + 256 < NSB) {
            lbase[i + 256] = hist[i + 256] - v1;
            gbase[i + 256] = (v1 > 0) ? atomicAdd(&cursor[i + 256], v1) : 0;
        }
        __syncthreads();
        #pragma unroll
        for (int k = 0; k < EPT; ++k) {
            if (keys[k] >= 0) {
                int p = lbase[keys[k]] + ranks[k];
                buf[p] = words[k];
                keyb[p] = (unsigned short)keys[k];
            }
        }
        __syncthreads();
        for (int j = threadIdx.x; j < cnt; j += 256) {
            int kk = keyb[j];
            out[gbase[kk] + (j - lbase[kk])] = buf[j];
        }
        __syncthreads();
    }
}

// one block per superbucket: per-node counting sort via LDS staging,
// sorted result copied to global with fully sequential coalesced stores.
__global__ void k_sb_sort(const int* __restrict__ sbptr, const int* __restrict__ packed,
                          int* __restrict__ csr_src, int* __restrict__ rowptr) {
    __shared__ int hist[SB_NODES];   // -> exclusive offsets -> cursors
    __shared__ int lbuf[CAP];
    int b = blockIdx.x;
    int e0 = sbptr[b], e1 = sbptr[b + 1];
    int cnt = e1 - e0;
    hist[threadIdx.x] = 0;
    __syncthreads();
    for (int j = e0 + threadIdx.x; j < e1; j += 256)
        atomicAdd(&hist[(packed[j] >> 17) & (SB_NODES - 1)], 1);
    __syncthreads();
    // 256-slot inclusive scan, one slot per thread
    int i = threadIdx.x;
    int v = hist[i];
    for (int o = 1; o < 256; o <<= 1) {
        int a = (i >= o) ? hist[i - o] : 0;
        __syncthreads();
        hist[i] += a;
        __syncthreads();
    }
    int excl = hist[i] - v;
    int node = (b << SB_BITS) + i;
    if (node < NN) rowptr[node] = e0 + excl;
    hist[i] = excl;                   // becomes cursor
    if (b == 0 && i == 0) rowptr[NN] = EE;
    __syncthreads();
    if (cnt <= CAP) {
        for (int j = e0 + threadIdx.x; j < e1; j += 256) {
            int w = packed[j];
            int n = (w >> 17) & (SB_NODES - 1);
            int pos = atomicAdd(&hist[n], 1);
            lbuf[pos] = w & 0x1FFFF;
        }
        __syncthreads();
        for (int j = threadIdx.x; j < cnt; j += 256)
            csr_src[e0 + j] = lbuf[j];           // sequential coalesced
    } else {
        // overflow fallback (unreachable for this input): direct global scatter
        for (int j = e0 + threadIdx.x; j < e1; j += 256) {
            int w = packed[j];
            int n = (w >> 17) & (SB_NODES - 1);
            int pos = atomicAdd(&hist[n], 1);
            csr_src[e0 + pos] = w & 0x1FFFF;
        }
    }
}

// ---------------- GNN compute ----------------

// which = blockIdx.x & 1 (BLOCK-uniform -> W reads scalarize to s_load).
// One thread per node, 32 fp32 accumulators; h rows staged through LDS.
// which==0: t_bf[node] = bf16(h[node]@Wn) ; which==1: hout[node] = h[node]@Ws + bn
// (R9 structure: 28 VGPR, no bank conflicts; only the which==0 store changed.)
template <int DIN>
__global__ __launch_bounds__(256) void k_transform(
        const float* __restrict__ h,
        const float* __restrict__ Wn,
        const float* __restrict__ Ws,
        const float* __restrict__ bn,
        unsigned* __restrict__ t_bf,
        float* __restrict__ hout) {
    constexpr int KC = 16;
    __shared__ float hs[256 * (KC + 1)];
    const int which = blockIdx.x & 1;              // block-uniform
    const int node = (blockIdx.x >> 1) * 256 + threadIdx.x;
    const bool valid = node < NN;
    const float* __restrict__ W = which ? Ws : Wn; // uniform pointer
    const float* __restrict__ hr = h + (size_t)(valid ? node : NN - 1) * DIN;
    float acc[32];
    #pragma unroll
    for (int d = 0; d < 32; ++d) acc[d] = 0.f;
    for (int kc = 0; kc < DIN; kc += KC) {
        __syncthreads();
        #pragma unroll
        for (int j = 0; j < KC / 4; ++j) {
            float4 f = *(const float4*)(hr + kc + j * 4);
            hs[threadIdx.x * (KC + 1) + j * 4 + 0] = f.x;
            hs[threadIdx.x * (KC + 1) + j * 4 + 1] = f.y;
            hs[threadIdx.x * (KC + 1) + j * 4 + 2] = f.z;
            hs[threadIdx.x * (KC + 1) + j * 4 + 3] = f.w;
        }
        __syncthreads();
        #pragma unroll
        for (int kk = 0; kk < KC; ++kk) {
            float f = hs[threadIdx.x * (KC + 1) + kk];
            const float* __restrict__ w0 = W + (kc + kk) * 32;  // uniform -> s_load
            #pragma unroll
            for (int d = 0; d < 32; ++d) acc[d] = fmaf(f, w0[d], acc[d]);
        }
    }
    if (valid) {
        if (which) {
            float* __restrict__ hp = hout + (size_t)node * 32;
            #pragma unroll
            for (int d = 0; d < 32; d += 4)
                *(float4*)(hp + d) = make_float4(acc[d] + bn[d], acc[d + 1] + bn[d + 1],
                                                 acc[d + 2] + bn[d + 2], acc[d + 3] + bn[d + 3]);
        } else {
            unsigned tb[16];
            #pragma unroll
            for (int d = 0; d < 16; ++d) tb[d] = pk_bf2(acc[2 * d], acc[2 * d + 1]);
            unsigned* tp = t_bf + (size_t)node * 16;
            #pragma unroll
            for (int d = 0; d < 16; d += 4)
                *(uint4*)(tp + d) = make_uint4(tb[d], tb[d + 1], tb[d + 2], tb[d + 3]);
        }
    }
}

// 8 lanes per node, one bf16x4 (uint2, 8B) per lane = 64B/row = 1 line/edge.
// fp32 accumulate, 4-deep unroll: hout = relu(hout + seg_sum(t))
__global__ void k_aggregate(const int* __restrict__ rowptr,
                            const int* __restrict__ csr_src,
                            const uint2* __restrict__ t2,
                            float4* __restrict__ hout4) {
    int node = blockIdx.x * 32 + (threadIdx.x >> 3);
    int q = threadIdx.x & 7;
    if (node >= NN) return;
    int j = rowptr[node];
    int end = rowptr[node + 1];
    float4 a0 = make_float4(0.f, 0.f, 0.f, 0.f);
    float4 a1 = a0, a2 = a0, a3 = a0;
    for (; j + 4 <= end; j += 4) {
        int s0 = csr_src[j];
        int s1 = csr_src[j + 1];
        int s2 = csr_src[j + 2];
        int s3 = csr_src[j + 3];
        uint2 u0 = t2[s0 * 8 + q];
        uint2 u1 = t2[s1 * 8 + q];
        uint2 u2 = t2[s2 * 8 + q];
        uint2 u3 = t2[s3 * 8 + q];
        a0.x += __uint_as_float(u0.x << 16); a0.y += __uint_as_float(u0.x & 0xFFFF0000u);
        a0.z += __uint_as_float(u0.y << 16); a0.w += __uint_as_float(u0.y & 0xFFFF0000u);
        a1.x += __uint_as_float(u1.x << 16); a1.y += __uint_as_float(u1.x & 0xFFFF0000u);
        a1.z += __uint_as_float(u1.y << 16); a1.w += __uint_as_float(u1.y & 0xFFFF0000u);
        a2.x += __uint_as_float(u2.x << 16); a2.y += __uint_as_float(u2.x & 0xFFFF0000u);
        a2.z += __uint_as_float(u2.y << 16); a2.w += __uint_as_float(u2.y & 0xFFFF0000u);
        a3.x += __uint_as_float(u3.x << 16); a3.y += __uint_as_float(u3.x & 0xFFFF0000u);
        a3.z += __uint_as_float(u3.y << 16); a3.w += __uint_as_float(u3.y & 0xFFFF0000u);
    }
    for (; j < end; ++j) {
        uint2 u = t2[csr_src[j] * 8 + q];
        a0.x += __uint_as_float(u.x << 16); a0.y += __uint_as_float(u.x & 0xFFFF0000u);
        a0.z += __uint_as_float(u.y << 16); a0.w += __uint_as_float(u.y & 0xFFFF0000u);
    }
    float4 s = add4(add4(a0, a1), add4(a2, a3));
    int idx = node * 8 + q;
    float4 h = hout4[idx];
    h.x = fmaxf(h.x + s.x, 0.f);
    h.y = fmaxf(h.y + s.y, 0.f);
    h.z = fmaxf(h.z + s.z, 0.f);
    h.w = fmaxf(h.w + s.w, 0.f);
    hout4[idx] = h;
}

// concat(x,h1,h2,h3) @ fc_w + fc_b -> log_softmax
__global__ void k_final(const float* __restrict__ x,
                        const float* __restrict__ h1,
                        const float* __restrict__ h2,
                        const float* __restrict__ h3,
                        const float* __restrict__ fc_w,
                        const float* __restrict__ fc_b,
                        float* __restrict__ out) {
    __shared__ float Wl[224 * 10];
    __shared__ float bl[10];
    for (int i = threadIdx.x; i < 224 * 10; i += blockDim.x) Wl[i] = fc_w[i];
    if (threadIdx.x < 10) bl[threadIdx.x] = fc_b[threadIdx.x];
    __syncthreads();
    int n = blockIdx.x * blockDim.x + threadIdx.x;
    if (n >= NN) return;
    float acc[10];
    #pragma unroll
    for (int c = 0; c < 10; ++c) acc[c] = bl[c];
    const float* xr = x + (size_t)n * 128;
    for (int j = 0; j < 128; ++j) {
        float f = xr[j];
        #pragma unroll
        for (int c = 0; c < 10; ++c) acc[c] += f * Wl[j * 10 + c];
    }
    const float* hs[3] = {h1, h2, h3};
    for (int l = 0; l < 3; ++l) {
        const float* hr = hs[l] + (size_t)n * 32;
        for (int j = 0; j < 32; ++j) {
            float f = hr[j];
            #pragma unroll
            for (int c = 0; c < 10; ++c) acc[c] += f * Wl[(128 + l * 32 + j) * 10 + c];
        }
    }
    float m = acc[0];
    #pragma unroll
    for (int c = 1; c < 10; ++c) m = fmaxf(m, acc[c]);
    float s = 0.f;
    #pragma unroll
    for (int c = 0; c < 10; ++c) s += __expf(acc[c] - m);
    float ls = __logf(s);
    #pragma unroll
    for (int c = 0; c < 10; ++c) out[n * 10 + c] = acc[c] - m - ls;
}

extern "C" void kernel_launch(void* const* d_in, const int* in_sizes, int n_in,
                              void* d_out, int out_size, void* d_ws, size_t ws_size,
                              hipStream_t stream) {
    const float* x   = (const float*)d_in[0];
    const int*   src = (const int*)d_in[1];
    const int*   dst = (const int*)d_in[2];
    const float* Wn[3] = {(const float*)d_in[3], (const float*)d_in[6], (const float*)d_in[9]};
    const float* bn[3] = {(const float*)d_in[4], (const float*)d_in[7], (const float*)d_in[10]};
    const float* Ws[3] = {(const float*)d_in[5], (const float*)d_in[8], (const float*)d_in[11]};
    const float* fc_w = (const float*)d_in[12];
    const float* fc_b = (const float*)d_in[13];
    float* out = (float*)d_out;

    // workspace layout (packed aliases h3: packed is dead before h3 is written)
    char* w = (char*)d_ws;
    const size_t NF = (size_t)NN * 32;
    unsigned* t_bf = (unsigned*)w;              w += (size_t)NN * 16 * 4;  // 6.4 MB (bf16 t)
    float* h1  = (float*)w;                     w += NF * 4;
    float* h2  = (float*)w;                     w += NF * 4;
    float* h3  = (float*)w;                     w += NF * 4;
    int* csr_src = (int*)w;                     w += (size_t)EE * 4;  // 12.8 MB
    int* scnt   = (int*)w;                      w += (size_t)NSB * 4;
    int* sbptr  = (int*)w;                      w += (size_t)(NSB + 1) * 4;
    int* cursor = (int*)w;                      w += (size_t)NSB * 4;
    int* rowptr = (int*)w;                      w += (size_t)(NN + 1) * 4;
    int* packed = (int*)h3;   // temp, consumed by k_sb_sort before layers run

    // ---- CSR build: multisplit into 391 superbuckets + in-LDS counting sort ----
    hipMemsetAsync(scnt, 0, (size_t)NSB * 4, stream);
    k_hist_sb<<<512, 256, 0, stream>>>(dst, scnt);
    k_scan_sb<<<1, 256, 0, stream>>>(scnt, sbptr, cursor);
    k_split<<<512, 256, 0, stream>>>(src, dst, cursor, packed);
    k_sb_sort<<<NSB, 256, 0, stream>>>(sbptr, packed, csr_src, rowptr);

    // ---- layers ----
    const int tr_blocks = 2 * ((NN + 255) / 256);              // 782 (which in bit 0)
    const int ag_blocks = (NN + 31) / 32;
    k_transform<128><<<tr_blocks, 256, 0, stream>>>(x, Wn[0], Ws[0], bn[0], t_bf, h1);
    k_aggregate<<<ag_blocks, 256, 0, stream>>>(rowptr, csr_src, (const uint2*)t_bf, (float4*)h1);
    k_transform<32><<<tr_blocks, 256, 0, stream>>>(h1, Wn[1], Ws[1], bn[1], t_bf, h2);
    k_aggregate<<<ag_blocks, 256, 0, stream>>>(rowptr, csr_src, (const uint2*)t_bf, (float4*)h2);
    k_transform<32><<<tr_blocks, 256, 0, stream>>>(h2, Wn[2], Ws[2], bn[2], t_bf, h3);
    k_aggregate<<<ag_blocks, 256, 0, stream>>>(rowptr, csr_src, (const uint2*)t_bf, (float4*)h3);
    k_final<<<(NN + 255) / 256, 256, 0, stream>>>(x, h1, h2, h3, fc_w, fc_b, out);
}